// Round 9
// baseline (55.504 us; speedup 1.0000x reference)
//
#include <hip/hip_runtime.h>
#include <stdint.h>

// x: [64, 512, 32, 32] f32. 65536 pixels, 512 channels, K=52.
// Fully-resident persistent pipeline: 1024 blocks x 512 thr = exactly 4
// blocks/CU (launch_bounds(512,8), 33KB LDS), 4 tiles each, no turnover.
// Per tile: raw lgkm barrier -> write prefetched regs->LDS -> raw barrier ->
// issue next tile's loads -> extract pixel regs -> selection (~900cy cover).
// Selection (R6-proven): early compact to >=0.75 set, 2 fixed + 2 adaptive
// ballot probes, dual-pixel 32-lane bitonic on <=32 survivors, tie-exact
// top-sum; bounded wave-uniform fallbacks => exact for any input.

#define NCH 512
#define K_TOP 52
#define PIX_PER_BLK 16
#define NTILES 4096
#define NPERS  1024
#define NT     (NTILES / NPERS)    // 4
#define LDS_STRIDE 516

#define LO_BITS   0x3F400000u  // 0.75f
#define P175_BITS 0x3FE00000u  // 1.75f
#define P125_BITS 0x3FA00000u  // 1.25f
#define INF_BITS  0x7F800000u
#define CAP_C0    192          // 3 regs * 64 lanes

#define LGKM0_BARRIER() do { \
    asm volatile("s_waitcnt lgkmcnt(0)" ::: "memory"); \
    __builtin_amdgcn_s_barrier(); \
    asm volatile("" ::: "memory"); \
} while (0)

static __device__ __forceinline__ int mbcnt64(uint64_t m) {
    return (int)__builtin_amdgcn_mbcnt_hi((uint32_t)(m >> 32),
            __builtin_amdgcn_mbcnt_lo((uint32_t)m, 0u));
}

__device__ __forceinline__ int count_ge8(const uint32_t u[8], uint32_t midv) {
    int c = 0;
    #pragma unroll
    for (int j = 0; j < 8; ++j)
        c += (int)__popcll(__ballot(u[j] >= midv));
    return c;
}
__device__ __forceinline__ int count_ge3(const uint32_t c3[3], uint32_t midv) {
    int c = 0;
    #pragma unroll
    for (int j = 0; j < 3; ++j)
        c += (int)__popcll(__ballot(c3[j] >= midv));
    return c;
}
__device__ __forceinline__ void bs_step8(const uint32_t u[8], uint32_t& lo, uint32_t& hi,
                                         int& clo, int& ctop) {
    const uint32_t midv = (lo + hi + 1u) >> 1;
    const int cnt = count_ge8(u, midv);
    const bool ge = (cnt >= K_TOP);
    lo = ge ? midv : lo;        clo  = ge ? cnt  : clo;
    hi = ge ? hi : (midv - 1u); ctop = ge ? ctop : cnt;
}
__device__ __forceinline__ void bs_step3(const uint32_t c3[3], uint32_t& lo, uint32_t& hi,
                                         int& clo, int& ctop) {
    const uint32_t midv = (lo + hi + 1u) >> 1;
    const int cnt = count_ge3(c3, midv);
    const bool ge = (cnt >= K_TOP);
    lo = ge ? midv : lo;        clo  = ge ? cnt  : clo;
    hi = ge ? hi : (midv - 1u); ctop = ge ? ctop : cnt;
}
__device__ __forceinline__ void probe3(const uint32_t c3[3], uint32_t& lo, uint32_t& hi,
                                       int& clo, int& ctop, uint32_t midv) {
    const int cnt = count_ge3(c3, midv);
    const bool valid = (midv > lo) && (midv <= hi);
    const bool ge = valid && (cnt >= K_TOP);
    const bool lt = valid && (cnt < K_TOP);
    lo = ge ? midv : lo;        clo  = ge ? cnt : clo;
    hi = lt ? (midv - 1u) : hi; ctop = lt ? cnt : ctop;
}

__global__ __launch_bounds__(512, 8) void hah_select_kernel(const float* __restrict__ x,
                                                            float* __restrict__ ws) {
    __shared__ float buf[PIX_PER_BLK * LDS_STRIDE];   // 33 KB
    __shared__ float red_w[8];
    __shared__ float red_r[8];
    uint32_t* const ldsu = (uint32_t*)buf;

    const int t    = threadIdx.x;
    const int lane = t & 63;
    const int w    = t >> 6;                 // wave 0..7
    const int pbid = blockIdx.x;
    // XCD-chunked bijective swizzle over persistent blocks (1024 % 8 == 0)
    const int swz  = (pbid & 7) * (NPERS >> 3) + (pbid >> 3);

    const int n_local = t >> 2;              // 0..127
    const int p0      = (t & 3) * 4;         // 0,4,8,12
    const int row     = w * 2;

    float relu_acc = 0.0f;   // per-thread
    float sgt_acc  = 0.0f;   // per-lane
    float topc_acc = 0.0f;   // wave-uniform

    // ---- prologue: issue loads for tile(it=0) ----
    float4 vv[4];
    {
        const int pg = swz * PIX_PER_BLK;
        const float* __restrict__ xb = x + (size_t)(pg >> 10) * (NCH * 1024);
        const int pix0 = pg & 1023;
        #pragma unroll
        for (int c = 0; c < 4; ++c)
            vv[c] = *reinterpret_cast<const float4*>(xb + (size_t)(c * 128 + n_local) * 1024 + pix0 + p0);
    }

    #pragma unroll 1
    for (int it = 0; it < NT; ++it) {
        // step 1: all waves done reading the buffer (raw barrier, NO vmcnt drain)
        LGKM0_BARRIER();

        // step 2: write prefetched tile -> LDS (vmcnt waits land here, covered
        // by previous iteration's selection)
        #pragma unroll
        for (int c = 0; c < 4; ++c) {
            const int n = c * 128 + n_local;
            const float r0 = fmaxf(vv[c].x, 0.0f), r1 = fmaxf(vv[c].y, 0.0f);
            const float r2 = fmaxf(vv[c].z, 0.0f), r3 = fmaxf(vv[c].w, 0.0f);
            buf[(p0 + 0) * LDS_STRIDE + n] = r0;
            buf[(p0 + 1) * LDS_STRIDE + n] = r1;
            buf[(p0 + 2) * LDS_STRIDE + n] = r2;
            buf[(p0 + 3) * LDS_STRIDE + n] = r3;
            relu_acc += (r0 + r1) + (r2 + r3);
        }

        // step 3: staged tile visible to all waves
        LGKM0_BARRIER();

        // step 4: issue next tile's loads FIRST (before any lgkm-waiting ds_read)
        if (it + 1 < NT) {
            const int pg = ((it + 1) * NPERS + swz) * PIX_PER_BLK;
            const float* __restrict__ xb = x + (size_t)(pg >> 10) * (NCH * 1024);
            const int pix0 = pg & 1023;
            #pragma unroll
            for (int c = 0; c < 4; ++c)
                vv[c] = *reinterpret_cast<const float4*>(xb + (size_t)(c * 128 + n_local) * 1024 + pix0 + p0);
        }
        __builtin_amdgcn_sched_barrier(0);   // keep loads issued here, not sunk

        // step 5: extract this wave's 2 pixels to registers
        uint32_t u[2][8];
        #pragma unroll
        for (int i = 0; i < 2; ++i)
            #pragma unroll
            for (int j = 0; j < 8; ++j)
                u[i][j] = __float_as_uint(buf[(row + i) * LDS_STRIDE + j * 64 + lane]);

        // ================= step 6: selection (wave-own scratch rows) =========
        int c0[2];
        #pragma unroll
        for (int i = 0; i < 2; ++i) c0[i] = count_ge8(u[i], LO_BITS);

        const bool wavefast =
            (c0[0] >= K_TOP) && (c0[0] <= CAP_C0) && (c0[1] >= K_TOP) && (c0[1] <= CAP_C0);

        if (!wavefast) {
            // exact fallback: full 31-step bisection on the 8-reg set
            uint32_t lo[2], hi[2]; int clo[2], ctop[2];
            #pragma unroll
            for (int i = 0; i < 2; ++i) { lo[i] = 0u; hi[i] = INF_BITS; clo[i] = NCH; ctop[i] = 0; }
            #pragma unroll 1
            for (int s = 0; s < 31; ++s) {
                #pragma unroll
                for (int i = 0; i < 2; ++i) bs_step8(u[i], lo[i], hi[i], clo[i], ctop[i]);
            }
            #pragma unroll
            for (int i = 0; i < 2; ++i) {
                const uint32_t T = lo[i];
                const int cgt = count_ge8(u[i], T + 1u);
                #pragma unroll
                for (int j = 0; j < 8; ++j)
                    sgt_acc += (u[i][j] > T) ? __uint_as_float(u[i][j]) : 0.0f;
                topc_acc += (float)(K_TOP - cgt) * __uint_as_float(T);
            }
        } else {
            // early compact: values >= 0.75 into this wave's own rows
            #pragma unroll
            for (int i = 0; i < 2; ++i)
                #pragma unroll
                for (int r = 0; r < 3; ++r)
                    ldsu[(row + i) * LDS_STRIDE + r * 64 + lane] = 0u;
            #pragma unroll
            for (int i = 0; i < 2; ++i) {
                int base = 0;
                #pragma unroll
                for (int j = 0; j < 8; ++j) {
                    const bool pred = (u[i][j] >= LO_BITS);
                    const uint64_t mk = __ballot(pred);
                    const int pre = mbcnt64(mk);
                    if (pred) ldsu[(row + i) * LDS_STRIDE + base + pre] = u[i][j];
                    base += (int)__popcll(mk);
                }
            }
            uint32_t c3[2][3];
            #pragma unroll
            for (int i = 0; i < 2; ++i)
                #pragma unroll
                for (int r = 0; r < 3; ++r)
                    c3[i][r] = ldsu[(row + i) * LDS_STRIDE + r * 64 + lane];

            // bracket: 2 fixed probes + 2 adaptive bisections
            uint32_t lo[2], hi[2]; int clo[2], ctop[2];
            #pragma unroll
            for (int i = 0; i < 2; ++i) { lo[i] = LO_BITS; hi[i] = INF_BITS; clo[i] = c0[i]; ctop[i] = 0; }
            #pragma unroll
            for (int i = 0; i < 2; ++i) probe3(c3[i], lo[i], hi[i], clo[i], ctop[i], P175_BITS);
            #pragma unroll
            for (int i = 0; i < 2; ++i) probe3(c3[i], lo[i], hi[i], clo[i], ctop[i], P125_BITS);
            #pragma unroll
            for (int i = 0; i < 2; ++i) bs_step3(c3[i], lo[i], hi[i], clo[i], ctop[i]);
            #pragma unroll
            for (int i = 0; i < 2; ++i) bs_step3(c3[i], lo[i], hi[i], clo[i], ctop[i]);

            const bool wavesmall = (clo[0] - ctop[0] <= 32) && (clo[1] - ctop[1] <= 32);

            uint32_t T[2]; int cgt[2];
            if (!wavesmall) {
                #pragma unroll 1
                for (int s = 0; s < 31; ++s) {
                    #pragma unroll
                    for (int i = 0; i < 2; ++i) bs_step3(c3[i], lo[i], hi[i], clo[i], ctop[i]);
                }
                #pragma unroll
                for (int i = 0; i < 2; ++i) { T[i] = lo[i]; cgt[i] = count_ge3(c3[i], lo[i] + 1u); }
            } else {
                // window compact (<=32) then dual-pixel 32-lane bitonic
                #pragma unroll
                for (int i = 0; i < 2; ++i)
                    ldsu[(row + i) * LDS_STRIDE + 256 + (lane & 31)] = 0u;
                #pragma unroll
                for (int i = 0; i < 2; ++i) {
                    int base = 0;
                    #pragma unroll
                    for (int r = 0; r < 3; ++r) {
                        const bool pred = (c3[i][r] >= lo[i]) && (c3[i][r] <= hi[i]);
                        const uint64_t mk = __ballot(pred);
                        const int pre = mbcnt64(mk);
                        if (pred) ldsu[(row + i) * LDS_STRIDE + 256 + base + pre] = c3[i][r];
                        base += (int)__popcll(mk);
                    }
                }
                // px0 candidates -> lanes 0..31, px1 -> lanes 32..63
                uint32_t a = ldsu[(row + (lane >> 5)) * LDS_STRIDE + 256 + (lane & 31)];
                const int l = lane & 31;
                #pragma unroll
                for (int k = 2; k <= 32; k <<= 1) {
                    #pragma unroll
                    for (int j = k >> 1; j >= 1; j >>= 1) {
                        const bool takeMax = ((l & k) == 0) == ((l & j) == 0);
                        const uint32_t o = (uint32_t)__shfl_xor((int)a, j, 64);
                        const uint32_t mx = a > o ? a : o, mn = a > o ? o : a;
                        a = takeMax ? mx : mn;
                    }
                }
                T[0] = (uint32_t)__shfl((int)a,      K_TOP - ctop[0] - 1, 64);
                T[1] = (uint32_t)__shfl((int)a, 32 + K_TOP - ctop[1] - 1, 64);
                const uint32_t tSel = (lane & 32) ? T[1] : T[0];
                const uint64_t mA = __ballot(a > tSel);
                cgt[0] = ctop[0] + (int)__builtin_popcount((uint32_t)mA);
                cgt[1] = ctop[1] + (int)__builtin_popcount((uint32_t)(mA >> 32));
            }

            // tie-exact top-sum from the compact set
            #pragma unroll
            for (int i = 0; i < 2; ++i) {
                #pragma unroll
                for (int r = 0; r < 3; ++r)
                    sgt_acc += (c3[i][r] > T[i]) ? __uint_as_float(c3[i][r]) : 0.0f;
                topc_acc += (float)(K_TOP - cgt[i]) * __uint_as_float(T[i]);
            }
        }
    }

    // ---- final block reduction (wave shuffles, tiny LDS) ----
    #pragma unroll
    for (int m = 32; m >= 1; m >>= 1) {
        sgt_acc  += __shfl_xor(sgt_acc,  m, 64);
        relu_acc += __shfl_xor(relu_acc, m, 64);
    }
    if (lane == 0) { red_w[w] = sgt_acc + topc_acc; red_r[w] = relu_acc; }
    __syncthreads();

    if (t == 0) {
        const float C1 = (1.0f / (float)K_TOP + 1.0f / (float)(NCH - K_TOP));
        const float C2 = (1.0f / (float)(NCH - K_TOP));
        float top = 0.0f, s4 = 0.0f;
        #pragma unroll
        for (int k = 0; k < 8; ++k) { top += red_w[k]; s4 += red_r[k]; }
        ws[pbid] = top * C1 - s4 * C2;
    }
}

__global__ void hah_reduce_kernel(const float* __restrict__ ws, float* __restrict__ out) {
    __shared__ float red[256];
    float s = 0.0f;
    #pragma unroll
    for (int k = 0; k < NPERS / 256; ++k) s += ws[threadIdx.x + 256 * k];
    red[threadIdx.x] = s;
    __syncthreads();
    for (int step = 128; step >= 1; step >>= 1) {
        if (threadIdx.x < step) red[threadIdx.x] += red[threadIdx.x + step];
        __syncthreads();
    }
    if (threadIdx.x == 0) out[0] = red[0] * (1.0f / 65536.0f);
}

extern "C" void kernel_launch(void* const* d_in, const int* in_sizes, int n_in,
                              void* d_out, int out_size, void* d_ws, size_t ws_size,
                              hipStream_t stream) {
    const float* x = (const float*)d_in[0];
    float* out = (float*)d_out;
    float* ws  = (float*)d_ws;   // 1024 float partials

    hah_select_kernel<<<NPERS, 512, 0, stream>>>(x, ws);
    hah_reduce_kernel<<<1, 256, 0, stream>>>(ws, out);
}

// Round 10
// 53.258 us; speedup vs baseline: 1.0422x; 1.0422x over previous
//
#include <hip/hip_runtime.h>
#include <stdint.h>

// x: [64, 512, 32, 32] f32. 65536 pixels, 512 channels, K=52.
// 512 persistent blocks x 512 thr = exactly 2 blocks/CU (75.8KB LDS), fully
// resident. Double-buffered global_load_lds DMA staging (zero VGPR cost),
// counted vmcnt(17) waits, raw barriers (no drain). LDS tile layout:
// word W = ch*17 + px (17-word rows: DMA-contiguous dest + 2-way-free banks).
// ReLU applied at extraction. Selection (R6-proven): early compact to >=0.75
// set, 2 fixed + 2 adaptive ballot probes, dual-pixel 32-lane bitonic on <=32
// survivors, tie-exact top-sum; bounded wave-uniform fallbacks => exact always.

#define NCH 512
#define K_TOP 52
#define PIX_PER_BLK 16
#define NTILES 4096
#define NPERS  512
#define NT     (NTILES / NPERS)    // 8
#define ROWW   17                  // words per channel row (16 px + 1 pad)
#define TILEW  (NCH * ROWW)        // 8704 words per tile buffer

#define LO_BITS   0x3F400000u  // 0.75f
#define P175_BITS 0x3FE00000u  // 1.75f
#define P125_BITS 0x3FA00000u  // 1.25f
#define INF_BITS  0x7F800000u
#define CAP_C0    192          // 3 regs * 64 lanes

// wait own prior-tile DMA (counted: next tile's 17 may stay in flight), then barrier
#define WAIT17_BARRIER() do { \
    asm volatile("s_waitcnt vmcnt(17)" ::: "memory"); \
    __builtin_amdgcn_s_barrier(); \
    asm volatile("" ::: "memory"); } while (0)
#define WAIT0_BARRIER() do { \
    asm volatile("s_waitcnt vmcnt(0)" ::: "memory"); \
    __builtin_amdgcn_s_barrier(); \
    asm volatile("" ::: "memory"); } while (0)
#define RAW_BARRIER() do { \
    asm volatile("" ::: "memory"); \
    __builtin_amdgcn_s_barrier(); \
    asm volatile("" ::: "memory"); } while (0)

__device__ __forceinline__ void dma_word(const float* gsrc, uint32_t* ldst) {
    __builtin_amdgcn_global_load_lds(
        (const __attribute__((address_space(1))) void*)gsrc,
        (__attribute__((address_space(3))) void*)ldst, 4, 0, 0);
}

static __device__ __forceinline__ int mbcnt64(uint64_t m) {
    return (int)__builtin_amdgcn_mbcnt_hi((uint32_t)(m >> 32),
            __builtin_amdgcn_mbcnt_lo((uint32_t)m, 0u));
}

__device__ __forceinline__ int count_ge8(const uint32_t u[8], uint32_t midv) {
    int c = 0;
    #pragma unroll
    for (int j = 0; j < 8; ++j)
        c += (int)__popcll(__ballot(u[j] >= midv));
    return c;
}
__device__ __forceinline__ int count_ge3(const uint32_t c3[3], uint32_t midv) {
    int c = 0;
    #pragma unroll
    for (int j = 0; j < 3; ++j)
        c += (int)__popcll(__ballot(c3[j] >= midv));
    return c;
}
__device__ __forceinline__ void bs_step8(const uint32_t u[8], uint32_t& lo, uint32_t& hi,
                                         int& clo, int& ctop) {
    const uint32_t midv = (lo + hi + 1u) >> 1;
    const int cnt = count_ge8(u, midv);
    const bool ge = (cnt >= K_TOP);
    lo = ge ? midv : lo;        clo  = ge ? cnt  : clo;
    hi = ge ? hi : (midv - 1u); ctop = ge ? ctop : cnt;
}
__device__ __forceinline__ void bs_step3(const uint32_t c3[3], uint32_t& lo, uint32_t& hi,
                                         int& clo, int& ctop) {
    const uint32_t midv = (lo + hi + 1u) >> 1;
    const int cnt = count_ge3(c3, midv);
    const bool ge = (cnt >= K_TOP);
    lo = ge ? midv : lo;        clo  = ge ? cnt  : clo;
    hi = ge ? hi : (midv - 1u); ctop = ge ? ctop : cnt;
}
__device__ __forceinline__ void probe3(const uint32_t c3[3], uint32_t& lo, uint32_t& hi,
                                       int& clo, int& ctop, uint32_t midv) {
    const int cnt = count_ge3(c3, midv);
    const bool valid = (midv > lo) && (midv <= hi);
    const bool ge = valid && (cnt >= K_TOP);
    const bool lt = valid && (cnt < K_TOP);
    lo = ge ? midv : lo;        clo  = ge ? cnt : clo;
    hi = lt ? (midv - 1u) : hi; ctop = lt ? cnt : ctop;
}

__global__ __launch_bounds__(512, 4) void hah_select_kernel(const float* __restrict__ x,
                                                            float* __restrict__ ws) {
    __shared__ uint32_t buf0[TILEW];      // 34 KB
    __shared__ uint32_t buf1[TILEW];      // 34 KB
    __shared__ uint32_t scr[8][192];      // 6 KB wave-private selection scratch
    __shared__ float red_w[8];
    __shared__ float red_r[8];

    const int t    = threadIdx.x;
    const int lane = t & 63;
    const int w    = t >> 6;                 // wave 0..7
    const int pbid = blockIdx.x;
    // XCD-chunked bijective swizzle (512 % 8 == 0)
    const int swz  = (pbid & 7) * (NPERS >> 3) + (pbid >> 3);

    uint32_t* const scrw = scr[w];

    // ---- per-lane DMA source offsets (tile-invariant): LDS word W=1088w+64k+lane
    // holds channel 64w + (64k+lane)/17, pixel (64k+lane)%17 (pad px16 -> clamp)
    uint32_t off[17];
    #pragma unroll
    for (int k = 0; k < 17; ++k) {
        const uint32_t M  = 64u * k + (uint32_t)lane;
        const uint32_t q  = (M * 3856u) >> 16;       // exact M/17 for M<4096
        uint32_t px = M - q * 17u;
        px &= 15u;                                    // pad slot -> safe dup
        off[k] = q * 1024u + px;
    }

    float relu_acc = 0.0f;   // per-thread
    float sgt_acc  = 0.0f;   // per-lane
    float topc_acc = 0.0f;   // wave-uniform

    // ---- prologue: DMA tile 0 into buf0 ----
    {
        const int pg = swz * PIX_PER_BLK;
        const float* xb = x + ((size_t)(pg >> 10) * NCH + 64 * w) * 1024 + (pg & 1023);
        #pragma unroll
        for (int k = 0; k < 17; ++k)
            dma_word(xb + off[k], buf0 + 1088 * w + 64 * k);
    }

    #pragma unroll 1
    for (int it = 0; it < NT; ++it) {
        uint32_t* const bufc = (it & 1) ? buf1 : buf0;
        uint32_t* const bufn = (it & 1) ? buf0 : buf1;

        // ---- issue next tile's DMA into the other buffer (stays in flight) ----
        if (it + 1 < NT) {
            const int pg = ((it + 1) * NPERS + swz) * PIX_PER_BLK;
            const float* xb = x + ((size_t)(pg >> 10) * NCH + 64 * w) * 1024 + (pg & 1023);
            #pragma unroll
            for (int k = 0; k < 17; ++k)
                dma_word(xb + off[k], bufn + 1088 * w + 64 * k);
            WAIT17_BARRIER();     // own current-tile DMA done; all waves synced
        } else {
            WAIT0_BARRIER();
        }

        // ---- extract this wave's 2 pixels (ReLU at read) ----
        const int base_e = 17 * lane + 2 * w;
        uint32_t u[2][8];
        #pragma unroll
        for (int i = 0; i < 2; ++i) {
            #pragma unroll
            for (int j = 0; j < 8; ++j) {
                const float f = fmaxf(__uint_as_float(bufc[1088 * j + base_e + i]), 0.0f);
                u[i][j] = __float_as_uint(f);
                relu_acc += f;
            }
        }

        // ================= selection (wave-private scratch) =================
        int c0[2];
        #pragma unroll
        for (int i = 0; i < 2; ++i) c0[i] = count_ge8(u[i], LO_BITS);

        const bool wavefast =
            (c0[0] >= K_TOP) && (c0[0] <= CAP_C0) && (c0[1] >= K_TOP) && (c0[1] <= CAP_C0);

        if (!wavefast) {
            // exact fallback: full 31-step bisection on the 8-reg set
            uint32_t lo[2], hi[2]; int clo[2], ctop[2];
            #pragma unroll
            for (int i = 0; i < 2; ++i) { lo[i] = 0u; hi[i] = INF_BITS; clo[i] = NCH; ctop[i] = 0; }
            #pragma unroll 1
            for (int s = 0; s < 31; ++s) {
                #pragma unroll
                for (int i = 0; i < 2; ++i) bs_step8(u[i], lo[i], hi[i], clo[i], ctop[i]);
            }
            #pragma unroll
            for (int i = 0; i < 2; ++i) {
                const uint32_t T = lo[i];
                const int cgt = count_ge8(u[i], T + 1u);
                #pragma unroll
                for (int j = 0; j < 8; ++j)
                    sgt_acc += (u[i][j] > T) ? __uint_as_float(u[i][j]) : 0.0f;
                topc_acc += (float)(K_TOP - cgt) * __uint_as_float(T);
            }
        } else {
            // early compact (px-sequential, same 192-word scratch)
            uint32_t c3[2][3];
            #pragma unroll
            for (int i = 0; i < 2; ++i) {
                scrw[lane] = 0u; scrw[64 + lane] = 0u; scrw[128 + lane] = 0u;
                int base = 0;
                #pragma unroll
                for (int j = 0; j < 8; ++j) {
                    const bool pred = (u[i][j] >= LO_BITS);
                    const uint64_t mk = __ballot(pred);
                    const int pre = mbcnt64(mk);
                    if (pred) scrw[base + pre] = u[i][j];
                    base += (int)__popcll(mk);
                }
                #pragma unroll
                for (int r = 0; r < 3; ++r) c3[i][r] = scrw[r * 64 + lane];
            }

            // bracket: 2 fixed probes + 2 adaptive bisections
            uint32_t lo[2], hi[2]; int clo[2], ctop[2];
            #pragma unroll
            for (int i = 0; i < 2; ++i) { lo[i] = LO_BITS; hi[i] = INF_BITS; clo[i] = c0[i]; ctop[i] = 0; }
            #pragma unroll
            for (int i = 0; i < 2; ++i) probe3(c3[i], lo[i], hi[i], clo[i], ctop[i], P175_BITS);
            #pragma unroll
            for (int i = 0; i < 2; ++i) probe3(c3[i], lo[i], hi[i], clo[i], ctop[i], P125_BITS);
            #pragma unroll
            for (int i = 0; i < 2; ++i) bs_step3(c3[i], lo[i], hi[i], clo[i], ctop[i]);
            #pragma unroll
            for (int i = 0; i < 2; ++i) bs_step3(c3[i], lo[i], hi[i], clo[i], ctop[i]);

            const bool wavesmall = (clo[0] - ctop[0] <= 32) && (clo[1] - ctop[1] <= 32);

            uint32_t T[2]; int cgt[2];
            if (!wavesmall) {
                #pragma unroll 1
                for (int s = 0; s < 31; ++s) {
                    #pragma unroll
                    for (int i = 0; i < 2; ++i) bs_step3(c3[i], lo[i], hi[i], clo[i], ctop[i]);
                }
                #pragma unroll
                for (int i = 0; i < 2; ++i) { T[i] = lo[i]; cgt[i] = count_ge3(c3[i], lo[i] + 1u); }
            } else {
                // window compact (<=32 each) then dual-pixel 32-lane bitonic
                scrw[lane] = 0u;   // slots 0..63: px0 -> 0..31, px1 -> 32..63
                #pragma unroll
                for (int i = 0; i < 2; ++i) {
                    int base = 0;
                    #pragma unroll
                    for (int r = 0; r < 3; ++r) {
                        const bool pred = (c3[i][r] >= lo[i]) && (c3[i][r] <= hi[i]);
                        const uint64_t mk = __ballot(pred);
                        const int pre = mbcnt64(mk);
                        if (pred) scrw[i * 32 + base + pre] = c3[i][r];
                        base += (int)__popcll(mk);
                    }
                }
                uint32_t a = scrw[lane];
                const int l = lane & 31;
                #pragma unroll
                for (int k = 2; k <= 32; k <<= 1) {
                    #pragma unroll
                    for (int j = k >> 1; j >= 1; j >>= 1) {
                        const bool takeMax = ((l & k) == 0) == ((l & j) == 0);
                        const uint32_t o = (uint32_t)__shfl_xor((int)a, j, 64);
                        const uint32_t mx = a > o ? a : o, mn = a > o ? o : a;
                        a = takeMax ? mx : mn;
                    }
                }
                T[0] = (uint32_t)__shfl((int)a,      K_TOP - ctop[0] - 1, 64);
                T[1] = (uint32_t)__shfl((int)a, 32 + K_TOP - ctop[1] - 1, 64);
                const uint32_t tSel = (lane & 32) ? T[1] : T[0];
                const uint64_t mA = __ballot(a > tSel);
                cgt[0] = ctop[0] + (int)__builtin_popcount((uint32_t)mA);
                cgt[1] = ctop[1] + (int)__builtin_popcount((uint32_t)(mA >> 32));
            }

            // tie-exact top-sum from the compact set
            #pragma unroll
            for (int i = 0; i < 2; ++i) {
                #pragma unroll
                for (int r = 0; r < 3; ++r)
                    sgt_acc += (c3[i][r] > T[i]) ? __uint_as_float(c3[i][r]) : 0.0f;
                topc_acc += (float)(K_TOP - cgt[i]) * __uint_as_float(T[i]);
            }
        }

        // all waves done reading bufc -> next iteration may DMA into it
        RAW_BARRIER();
    }

    // ---- final block reduction ----
    #pragma unroll
    for (int m = 32; m >= 1; m >>= 1) {
        sgt_acc  += __shfl_xor(sgt_acc,  m, 64);
        relu_acc += __shfl_xor(relu_acc, m, 64);
    }
    if (lane == 0) { red_w[w] = sgt_acc + topc_acc; red_r[w] = relu_acc; }
    __syncthreads();

    if (t == 0) {
        const float C1 = (1.0f / (float)K_TOP + 1.0f / (float)(NCH - K_TOP));
        const float C2 = (1.0f / (float)(NCH - K_TOP));
        float top = 0.0f, s4 = 0.0f;
        #pragma unroll
        for (int k = 0; k < 8; ++k) { top += red_w[k]; s4 += red_r[k]; }
        ws[pbid] = top * C1 - s4 * C2;
    }
}

__global__ void hah_reduce_kernel(const float* __restrict__ ws, float* __restrict__ out) {
    __shared__ float red[256];
    float s = 0.0f;
    #pragma unroll
    for (int k = 0; k < NPERS / 256; ++k) s += ws[threadIdx.x + 256 * k];
    red[threadIdx.x] = s;
    __syncthreads();
    for (int step = 128; step >= 1; step >>= 1) {
        if (threadIdx.x < step) red[threadIdx.x] += red[threadIdx.x + step];
        __syncthreads();
    }
    if (threadIdx.x == 0) out[0] = red[0] * (1.0f / 65536.0f);
}

extern "C" void kernel_launch(void* const* d_in, const int* in_sizes, int n_in,
                              void* d_out, int out_size, void* d_ws, size_t ws_size,
                              hipStream_t stream) {
    const float* x = (const float*)d_in[0];
    float* out = (float*)d_out;
    float* ws  = (float*)d_ws;   // 512 float partials

    hah_select_kernel<<<NPERS, 512, 0, stream>>>(x, ws);
    hah_reduce_kernel<<<1, 256, 0, stream>>>(ws, out);
}